// Round 1
// baseline (141.808 us; speedup 1.0000x reference)
//
#include <hip/hip_runtime.h>

// SSIM loss, fused. B=32, H=W=512, win=11, out = 1 - mean(SSIM map).
// Decomposition: 32 images x 2 column strips x 8 vertical bands = 512 blocks.
// Stage 1: vertical sliding moment sums (thread-per-column) -> LDS.
// Stage 2: horizontal sliding window in registers (8 cols/thread) -> SSIM -> acc.

#define HH 512
#define WW 512
#define WIN 11
#define OH 502
#define OW 502
#define STRIP_OUT 251
#define STRIP_IN 261          // 251 + 10 halo
#define VBROWS 63             // output rows per vertical band (last band: 61)
#define TY 8                  // band rows processed per LDS round-trip
#define LDS_STRIDE 45         // 5 quantities * 9 (k-stride 1, padded to 9)

__global__ __launch_bounds__(256)
void ssim_main(const float* __restrict__ pred, const float* __restrict__ targ,
               float* __restrict__ partial) {
    __shared__ float vs[STRIP_IN * LDS_STRIDE];   // 46980 B
    __shared__ float wred[4];

    const int tid   = threadIdx.x;
    const int b     = blockIdx.x;
    const int img   = b >> 4;
    const int strip = (b >> 3) & 1;
    const int vb    = b & 7;

    const int y0   = vb * VBROWS;
    const int y1   = min(OH, y0 + VBROWS);
    const int col0 = strip * STRIP_OUT;

    const float* P = pred + img * (HH * WW);
    const float* T = targ + img * (HH * WW);

    const int k   = tid & 7;        // stage-2: row within band
    const int cg  = tid >> 3;       // stage-2: column group
    const int x0  = cg * 8;         // local output col start
    const int nout = min(8, STRIP_OUT - x0);

    const float inv_np   = 1.0f / 121.0f;
    const float cov_norm = 121.0f / 120.0f;
    const float C1 = 1e-4f, C2 = 9e-4f;

    float acc = 0.0f;

    for (int yb = y0; yb < y1; yb += TY) {
        const int rows = min(TY, y1 - yb);

        // ---- Stage 1: vertical window sums for band rows [yb, yb+rows) ----
        for (int lx = tid; lx < STRIP_IN; lx += 256) {
            const int gx = col0 + lx;
            const float* p0 = P + gx;
            const float* t0 = T + gx;
            float sp = 0.f, st = 0.f, spp = 0.f, stt = 0.f, spt = 0.f;
            float kp[7], kt[7];
            #pragma unroll
            for (int r = 0; r < 10; ++r) {
                float p = p0[(yb + r) * WW];
                float t = t0[(yb + r) * WW];
                sp += p; st += t; spp += p * p; stt += t * t; spt += p * t;
                if (r < 7) { kp[r] = p; kt[r] = t; }
            }
            #pragma unroll
            for (int kk = 0; kk < TY; ++kk) {
                if (kk < rows) {
                    float p = p0[(yb + 10 + kk) * WW];
                    float t = t0[(yb + 10 + kk) * WW];
                    sp += p; st += t; spp += p * p; stt += t * t; spt += p * t;
                    float* v = &vs[lx * LDS_STRIDE + kk];
                    v[0]  = sp;
                    v[9]  = st;
                    v[18] = spp;
                    v[27] = stt;
                    v[36] = spt;
                    if (kk < 7) {
                        float pp = kp[kk], tt = kt[kk];
                        sp -= pp; st -= tt; spp -= pp * pp; stt -= tt * tt; spt -= pp * tt;
                    }
                }
            }
        }
        __syncthreads();

        // ---- Stage 2: horizontal sliding window + SSIM ----
        if (k < rows) {
            float s0 = 0.f, s1 = 0.f, s2 = 0.f, s3 = 0.f, s4 = 0.f;
            #pragma unroll
            for (int j = 0; j < WIN; ++j) {
                const float* v = &vs[(x0 + j) * LDS_STRIDE + k];
                s0 += v[0]; s1 += v[9]; s2 += v[18]; s3 += v[27]; s4 += v[36];
            }
            #pragma unroll
            for (int i = 0; i < 8; ++i) {
                if (i < nout) {
                    float ux  = s0 * inv_np, uy  = s1 * inv_np;
                    float uxx = s2 * inv_np, uyy = s3 * inv_np, uxy = s4 * inv_np;
                    float vx  = cov_norm * (uxx - ux * ux);
                    float vy  = cov_norm * (uyy - uy * uy);
                    float vxy = cov_norm * (uxy - ux * uy);
                    float A1 = 2.f * ux * uy + C1;
                    float A2 = 2.f * vxy + C2;
                    float B1 = ux * ux + uy * uy + C1;
                    float B2 = vx + vy + C2;
                    acc += (A1 * A2) / (B1 * B2);
                    if (i < 7) {
                        const float* va = &vs[(x0 + 11 + i) * LDS_STRIDE + k];
                        const float* vb2 = &vs[(x0 + i) * LDS_STRIDE + k];
                        s0 += va[0]  - vb2[0];
                        s1 += va[9]  - vb2[9];
                        s2 += va[18] - vb2[18];
                        s3 += va[27] - vb2[27];
                        s4 += va[36] - vb2[36];
                    }
                }
            }
        }
        __syncthreads();
    }

    // ---- Block reduction: wave shuffle -> LDS -> partial[block] ----
    #pragma unroll
    for (int off = 32; off > 0; off >>= 1) acc += __shfl_down(acc, off);
    if ((tid & 63) == 0) wred[tid >> 6] = acc;
    __syncthreads();
    if (tid == 0) partial[b] = wred[0] + wred[1] + wred[2] + wred[3];
}

__global__ __launch_bounds__(512)
void ssim_final(const float* __restrict__ partial, float* __restrict__ out) {
    __shared__ float wred[8];
    const int tid = threadIdx.x;
    float v = partial[tid];
    #pragma unroll
    for (int off = 32; off > 0; off >>= 1) v += __shfl_down(v, off);
    if ((tid & 63) == 0) wred[tid >> 6] = v;
    __syncthreads();
    if (tid == 0) {
        float t = 0.f;
        #pragma unroll
        for (int i = 0; i < 8; ++i) t += wred[i];
        out[0] = 1.0f - t / (32.0f * 502.0f * 502.0f);
    }
}

extern "C" void kernel_launch(void* const* d_in, const int* in_sizes, int n_in,
                              void* d_out, int out_size, void* d_ws, size_t ws_size,
                              hipStream_t stream) {
    const float* pred = (const float*)d_in[0];
    const float* targ = (const float*)d_in[1];
    float* out     = (float*)d_out;
    float* partial = (float*)d_ws;   // 512 floats of scratch

    ssim_main<<<dim3(512), dim3(256), 0, stream>>>(pred, targ, partial);
    ssim_final<<<dim3(1), dim3(512), 0, stream>>>(partial, out);
}

// Round 2
// 116.248 us; speedup vs baseline: 1.2199x; 1.2199x over previous
//
#include <hip/hip_runtime.h>

// SSIM loss, fused. B=32, H=W=512, win=11, out = 1 - mean(SSIM map).
// Grid: 32 images x 3 col strips (168/168/166 out) x 13 bands (40 rows) = 1248 blocks.
// 4 moments in LDS (p, t, p^2+t^2, p*t), row-major planes stride 180 -> b128 reads.
// 28.8 KB LDS + launch_bounds(256,5) -> 5 blocks/CU, all 1248 blocks co-resident.

#define WW 512
#define OH 502
#define LS 180                  // LDS plane stride in words (mult of 4, 20k mod 32 uniform)
#define NBANDS 13
#define BANDROWS 40

__global__ __launch_bounds__(256, 5)
void ssim_main(const float* __restrict__ Pg, const float* __restrict__ Tg,
               float* __restrict__ partial) {
    __shared__ float vs[32 * LS];   // 4 moments x 8 rows x 180 = 23040 floats? no: 32*180*4B = 23 KB

    const int tid = threadIdx.x;
    const int b   = blockIdx.x;
    const int img   = b / 39;            // 39 = 3 strips * 13 bands
    const int rem   = b - img * 39;
    const int strip = rem / NBANDS;
    const int vb    = rem - strip * NBANDS;

    const int outw = (strip == 2) ? 166 : 168;
    const int inw  = outw + 10;
    const int col0 = strip * 168;
    const int y0   = vb * BANDROWS;
    const int rowsband = min(BANDROWS, OH - y0);   // last band: 22

    const float* P = Pg + img * (WW * WW) + col0;
    const float* T = Tg + img * (WW * WW) + col0;

    const int k  = tid & 7;
    const int cg = tid >> 3;
    const int x0 = cg * 8;
    const int nout = outw - x0;          // <=0 for idle threads; clamp below

    const float NP  = 121.0f;
    const float cn  = 121.0f / 120.0f;
    const float C1n = 1e-4f * 121.0f * 121.0f;   // C1 * NP^2
    const float C2n = 9e-4f * 121.0f * 121.0f;   // C2 * NP^2

    float acc = 0.0f;

    for (int yb = y0; yb < y0 + rowsband; yb += 8) {
        const int rows = min(8, y0 + rowsband - yb);

        // ---- Stage 1: vertical window sums, thread-per-column ----
        if (tid < inw) {
            const float* p0 = P + tid;
            const float* t0 = T + tid;
            float sp = 0.f, st = 0.f, sq = 0.f, sx = 0.f;
            float kp[7], kt[7];
            #pragma unroll
            for (int rr = 0; rr < 10; ++rr) {
                float p = p0[(yb + rr) * WW];
                float t = t0[(yb + rr) * WW];
                sp += p; st += t;
                sq = fmaf(p, p, sq); sq = fmaf(t, t, sq);
                sx = fmaf(p, t, sx);
                if (rr < 7) { kp[rr] = p; kt[rr] = t; }
            }
            #pragma unroll
            for (int kk = 0; kk < 8; ++kk) {
                if (kk < rows) {
                    float p = p0[(yb + 10 + kk) * WW];
                    float t = t0[(yb + 10 + kk) * WW];
                    sp += p; st += t;
                    sq = fmaf(p, p, sq); sq = fmaf(t, t, sq);
                    sx = fmaf(p, t, sx);
                    vs[(0 * 8 + kk) * LS + tid] = sp;
                    vs[(1 * 8 + kk) * LS + tid] = st;
                    vs[(2 * 8 + kk) * LS + tid] = sq;
                    vs[(3 * 8 + kk) * LS + tid] = sx;
                    if (kk < 7) {
                        float pp = kp[kk], tt = kt[kk];
                        sp -= pp; st -= tt;
                        sq = fmaf(pp, -pp, sq); sq = fmaf(tt, -tt, sq);
                        sx = fmaf(pp, -tt, sx);
                    }
                }
            }
        }
        __syncthreads();

        // ---- Stage 2: horizontal sliding window (b128 LDS reads) + SSIM ----
        if (k < rows && nout > 0) {
            float wsum[4][8];
            #pragma unroll
            for (int q = 0; q < 4; ++q) {
                const float* base = &vs[(q * 8 + k) * LS + x0];
                float w[18];
                #pragma unroll
                for (int j4 = 0; j4 < 4; ++j4) {
                    float4 v = *(const float4*)(base + j4 * 4);
                    w[j4 * 4 + 0] = v.x; w[j4 * 4 + 1] = v.y;
                    w[j4 * 4 + 2] = v.z; w[j4 * 4 + 3] = v.w;
                }
                float2 v2 = *(const float2*)(base + 16);
                w[16] = v2.x; w[17] = v2.y;
                float s = 0.f;
                #pragma unroll
                for (int j = 0; j < 11; ++j) s += w[j];
                wsum[q][0] = s;
                #pragma unroll
                for (int i = 1; i < 8; ++i) { s += w[10 + i] - w[i - 1]; wsum[q][i] = s; }
            }
            #pragma unroll
            for (int i = 0; i < 8; ++i) {
                if (i < nout) {
                    float s0 = wsum[0][i], s1 = wsum[1][i];
                    float sqq = wsum[2][i], sxy = wsum[3][i];
                    float m1 = s0 * s1;
                    float q1 = fmaf(s1, s1, s0 * s0);
                    float A1 = fmaf(2.f, m1, C1n);
                    float B1 = q1 + C1n;
                    float t4 = fmaf(NP, sxy, -m1);
                    float A2 = fmaf(2.f * cn, t4, C2n);
                    float tB = fmaf(NP, sqq, -q1);
                    float B2 = fmaf(cn, tB, C2n);
                    acc = fmaf(A1 * A2, __builtin_amdgcn_rcpf(B1 * B2), acc);
                }
            }
        }
        __syncthreads();
    }

    // ---- Block reduction ----
    #pragma unroll
    for (int off = 32; off > 0; off >>= 1) acc += __shfl_down(acc, off);
    if ((tid & 63) == 0) vs[tid >> 6] = acc;   // reuse LDS (after final barrier)
    __syncthreads();
    if (tid == 0) partial[b] = vs[0] + vs[1] + vs[2] + vs[3];
}

__global__ __launch_bounds__(256)
void ssim_final(const float* __restrict__ partial, float* __restrict__ out) {
    __shared__ float wred[4];
    const int tid = threadIdx.x;
    float v = 0.f;
    #pragma unroll
    for (int j = 0; j < 5; ++j) {
        int idx = tid + j * 256;
        if (idx < 1248) v += partial[idx];
    }
    #pragma unroll
    for (int off = 32; off > 0; off >>= 1) v += __shfl_down(v, off);
    if ((tid & 63) == 0) wred[tid >> 6] = v;
    __syncthreads();
    if (tid == 0) {
        out[0] = 1.0f - (wred[0] + wred[1] + wred[2] + wred[3]) / 8064128.0f;
    }
}

extern "C" void kernel_launch(void* const* d_in, const int* in_sizes, int n_in,
                              void* d_out, int out_size, void* d_ws, size_t ws_size,
                              hipStream_t stream) {
    const float* pred = (const float*)d_in[0];
    const float* targ = (const float*)d_in[1];
    float* out     = (float*)d_out;
    float* partial = (float*)d_ws;   // 1248 floats of scratch

    ssim_main<<<dim3(1248), dim3(256), 0, stream>>>(pred, targ, partial);
    ssim_final<<<dim3(1), dim3(256), 0, stream>>>(partial, out);
}